// Round 1
// baseline (1377.525 us; speedup 1.0000x reference)
//
#include <hip/hip_runtime.h>
#include <hip/hip_bf16.h>

// GCN 4-layer: N=50000 nodes, E=800000 edges, dims 100->512->256->128->200
// Strategy: build CSR (by target col) in ws each call; per layer choose
// aggregate-first (L1: 100, L4: 128) or transform-first (L2: 256, L3: 128)
// to minimize scatter feature volume. fp32 tiled GEMM. Mean epilogue.

#define NN 50000
#define NE 800000

// ---------------- edge-index dtype detection ----------------
// int64 little-endian with values in [0, 50000) => every odd 32-bit word == 0.
// int32 => odd words are random indices, ~never all zero across 256 samples.
__global__ void detect_kernel(const unsigned* ei, int* flag) {
    __shared__ int nonzero;
    if (threadIdx.x == 0) nonzero = 0;
    __syncthreads();
    unsigned w = ei[2 * threadIdx.x + 1];
    if (w) atomicOr(&nonzero, 1);
    __syncthreads();
    if (threadIdx.x == 0) *flag = nonzero ? 0 : 1;  // 1 => int64
}

__global__ __launch_bounds__(256) void convert_kernel(
    const void* ei, const int* __restrict__ flag,
    int* __restrict__ row32, int* __restrict__ col32, unsigned* __restrict__ cnt) {
    int e = blockIdx.x * blockDim.x + threadIdx.x;
    if (e >= NE) return;
    int r, c;
    if (*flag) {
        const long long* p = (const long long*)ei;
        r = (int)p[e];
        c = (int)p[NE + e];
    } else {
        const int* p = (const int*)ei;
        r = p[e];
        c = p[NE + e];
    }
    row32[e] = r;
    col32[e] = c;
    atomicAdd(&cnt[c], 1u);
}

// dinv[i] = rsqrt(deg_in(i) + 1 self-loop); deg >= 1 always.
__global__ __launch_bounds__(256) void dinv_kernel(const unsigned* __restrict__ cnt,
                                                   float* __restrict__ dinv) {
    int i = blockIdx.x * blockDim.x + threadIdx.x;
    if (i >= NN) return;
    dinv[i] = rsqrtf((float)(cnt[i] + 1u));
}

// single-block exclusive scan over cnt -> off[0..NN], off[NN] = NE
__global__ __launch_bounds__(1024) void scan_kernel(const unsigned* __restrict__ cnt,
                                                    int* __restrict__ off) {
    __shared__ int sh[1024];
    __shared__ int carry;
    if (threadIdx.x == 0) carry = 0;
    __syncthreads();
    for (int base = 0; base < NN; base += 1024) {
        int i = base + threadIdx.x;
        int v = (i < NN) ? (int)cnt[i] : 0;
        sh[threadIdx.x] = v;
        __syncthreads();
        for (int d = 1; d < 1024; d <<= 1) {
            int t = (threadIdx.x >= d) ? sh[threadIdx.x - d] : 0;
            __syncthreads();
            sh[threadIdx.x] += t;
            __syncthreads();
        }
        int incl = sh[threadIdx.x];
        int base_carry = carry;
        if (i < NN) off[i] = base_carry + incl - v;
        __syncthreads();
        if (threadIdx.x == 1023) carry = base_carry + sh[1023];
        __syncthreads();
    }
    if (threadIdx.x == 0) off[NN] = carry;
}

__global__ __launch_bounds__(256) void fill_kernel(
    const int* __restrict__ row32, const int* __restrict__ col32,
    const int* __restrict__ off, unsigned* __restrict__ fillc,
    const float* __restrict__ dinv, int* __restrict__ srow, float* __restrict__ snorm) {
    int e = blockIdx.x * blockDim.x + threadIdx.x;
    if (e >= NE) return;
    int r = row32[e], c = col32[e];
    int pos = off[c] + (int)atomicAdd(&fillc[c], 1u);
    srow[pos] = r;
    snorm[pos] = dinv[r] * dinv[c];
}

// One wave per target node. acc[f] = dinv[c]^2*h[c][f] + sum_e norm_e*h[row_e][f]
// Optional fused bias+relu epilogue (transform-first layers).
template <int BIAS_RELU>
__global__ __launch_bounds__(256) void aggregate_kernel(
    const float* __restrict__ h, float* __restrict__ out,
    const int* __restrict__ off, const int* __restrict__ srow,
    const float* __restrict__ snorm, const float* __restrict__ dinv,
    const float* __restrict__ bias, int dim) {
    int gw = (int)((blockIdx.x * blockDim.x + threadIdx.x) >> 6);
    int lane = threadIdx.x & 63;
    if (gw >= NN) return;
    const int c = gw;
    const int s = off[c], e = off[c + 1];
    const float dc = dinv[c];
    const float selfw = dc * dc;
    for (int f = lane * 4; f < dim; f += 256) {
        float4 hv = *(const float4*)(h + (size_t)c * dim + f);
        float4 acc;
        acc.x = selfw * hv.x; acc.y = selfw * hv.y;
        acc.z = selfw * hv.z; acc.w = selfw * hv.w;
        for (int j = s; j < e; ++j) {
            int r = srow[j];
            float w = snorm[j];
            float4 v = *(const float4*)(h + (size_t)r * dim + f);
            acc.x = fmaf(w, v.x, acc.x);
            acc.y = fmaf(w, v.y, acc.y);
            acc.z = fmaf(w, v.z, acc.z);
            acc.w = fmaf(w, v.w, acc.w);
        }
        if (BIAS_RELU) {
            float4 b = *(const float4*)(bias + f);
            acc.x = fmaxf(acc.x + b.x, 0.f);
            acc.y = fmaxf(acc.y + b.y, 0.f);
            acc.z = fmaxf(acc.z + b.z, 0.f);
            acc.w = fmaxf(acc.w + b.w, 0.f);
        }
        *(float4*)(out + (size_t)c * dim + f) = acc;
    }
}

// fp32 tiled GEMM: C[M,N] = A[M,K] @ W[K,N]; 64x64 tile, BK=16, 4x4/thread.
template <int BIAS_RELU>
__global__ __launch_bounds__(256) void gemm_kernel(
    const float* __restrict__ A, const float* __restrict__ W,
    const float* __restrict__ bias, float* __restrict__ C,
    int M, int K, int N) {
    __shared__ float As[16][65];
    __shared__ float Bs[16][65];
    const int bm = blockIdx.y * 64;
    const int bn = blockIdx.x * 64;
    const int tx = threadIdx.x & 15;
    const int ty = threadIdx.x >> 4;
    float acc[4][4] = {};
    for (int k0 = 0; k0 < K; k0 += 16) {
#pragma unroll
        for (int i = 0; i < 4; i++) {
            int l = (int)threadIdx.x + 256 * i;
            int m = l >> 4, kk = l & 15;
            float v = 0.f;
            if (bm + m < M && k0 + kk < K) v = A[(size_t)(bm + m) * K + (k0 + kk)];
            As[kk][m] = v;
        }
#pragma unroll
        for (int i = 0; i < 4; i++) {
            int l = (int)threadIdx.x + 256 * i;
            int nn = l & 63, kk = l >> 6;
            float v = 0.f;
            if (k0 + kk < K && bn + nn < N) v = W[(size_t)(k0 + kk) * N + (bn + nn)];
            Bs[kk][nn] = v;
        }
        __syncthreads();
#pragma unroll
        for (int kk = 0; kk < 16; kk++) {
            float a[4], b[4];
#pragma unroll
            for (int i = 0; i < 4; i++) a[i] = As[kk][ty * 4 + i];
#pragma unroll
            for (int j = 0; j < 4; j++) b[j] = Bs[kk][tx * 4 + j];
#pragma unroll
            for (int i = 0; i < 4; i++)
#pragma unroll
                for (int j = 0; j < 4; j++) acc[i][j] = fmaf(a[i], b[j], acc[i][j]);
        }
        __syncthreads();
    }
#pragma unroll
    for (int i = 0; i < 4; i++) {
        int m = bm + ty * 4 + i;
        if (m >= M) continue;
#pragma unroll
        for (int j = 0; j < 4; j++) {
            int nn = bn + tx * 4 + j;
            if (nn >= N) continue;
            float v = acc[i][j];
            if (BIAS_RELU) {
                v += bias[nn];
                v = fmaxf(v, 0.f);
            }
            C[(size_t)m * N + nn] = v;
        }
    }
}

// mean over rows of [NN, 200] -> out[200] (out must be pre-zeroed)
__global__ __launch_bounds__(256) void mean_kernel(const float* __restrict__ h,
                                                   float* __restrict__ out) {
    __shared__ float s[200];
    for (int i = threadIdx.x; i < 200; i += blockDim.x) s[i] = 0.f;
    __syncthreads();
    const size_t total = (size_t)NN * 200;
    for (size_t idx = (size_t)blockIdx.x * blockDim.x + threadIdx.x; idx < total;
         idx += (size_t)gridDim.x * blockDim.x) {
        float v = h[idx];
        int col = (int)(idx % 200);
        atomicAdd(&s[col], v);
    }
    __syncthreads();
    for (int i = threadIdx.x; i < 200; i += blockDim.x)
        atomicAdd(&out[i], s[i] * (1.0f / (float)NN));
}

extern "C" void kernel_launch(void* const* d_in, const int* in_sizes, int n_in,
                              void* d_out, int out_size, void* d_ws, size_t ws_size,
                              hipStream_t stream) {
    const float* x  = (const float*)d_in[0];
    const void*  ei = d_in[1];
    const float* W1 = (const float*)d_in[2];
    const float* b1 = (const float*)d_in[3];
    const float* W2 = (const float*)d_in[4];
    const float* b2 = (const float*)d_in[5];
    const float* W3 = (const float*)d_in[6];
    const float* b3 = (const float*)d_in[7];
    const float* W4 = (const float*)d_in[8];
    const float* b4 = (const float*)d_in[9];
    float* out = (float*)d_out;

    char* ws = (char*)d_ws;
    size_t o = 0;
    auto alloc = [&](size_t bytes) -> void* {
        void* p = ws + o;
        o += (bytes + 255) & ~(size_t)255;
        return p;
    };
    int*      flag  = (int*)alloc(4);
    int*      row32 = (int*)alloc((size_t)NE * 4);
    int*      col32 = (int*)alloc((size_t)NE * 4);
    unsigned* cnt   = (unsigned*)alloc((size_t)NN * 4);
    int*      off   = (int*)alloc((size_t)(NN + 1) * 4);
    unsigned* fillc = (unsigned*)alloc((size_t)NN * 4);
    float*    dinv  = (float*)alloc((size_t)NN * 4);
    int*      srow  = (int*)alloc((size_t)NE * 4);
    float*    snorm = (float*)alloc((size_t)NE * 4);
    float*    bufA  = (float*)alloc((size_t)NN * 256 * 4);  // max dim 256
    float*    bufB  = (float*)alloc((size_t)NN * 512 * 4);  // max dim 512

    hipMemsetAsync(cnt, 0, (size_t)NN * 4, stream);
    hipMemsetAsync(fillc, 0, (size_t)NN * 4, stream);
    hipMemsetAsync(out, 0, 200 * 4, stream);

    const int EB = (NE + 255) / 256;              // 3125
    const int AGG_B = (NN * 64 + 255) / 256;      // 12500 (one wave/node)

    detect_kernel<<<1, 256, 0, stream>>>((const unsigned*)ei, flag);
    convert_kernel<<<EB, 256, 0, stream>>>(ei, flag, row32, col32, cnt);
    dinv_kernel<<<(NN + 255) / 256, 256, 0, stream>>>(cnt, dinv);
    scan_kernel<<<1, 1024, 0, stream>>>(cnt, off);
    fill_kernel<<<EB, 256, 0, stream>>>(row32, col32, off, fillc, dinv, srow, snorm);

    // L1 (aggregate-first): agg1 = A.x (dim 100) -> bufA; h1 = relu(agg1@W1+b1) -> bufB [NN,512]
    aggregate_kernel<0><<<AGG_B, 256, 0, stream>>>(x, bufA, off, srow, snorm, dinv, nullptr, 100);
    {
        dim3 g(512 / 64, (NN + 63) / 64);
        gemm_kernel<1><<<g, 256, 0, stream>>>(bufA, W1, b1, bufB, NN, 100, 512);
    }
    // L2 (transform-first): t2 = h1@W2 -> bufA [NN,256]; h2 = relu(A.t2+b2) -> bufB
    {
        dim3 g(256 / 64, (NN + 63) / 64);
        gemm_kernel<0><<<g, 256, 0, stream>>>(bufB, W2, nullptr, bufA, NN, 512, 256);
    }
    aggregate_kernel<1><<<AGG_B, 256, 0, stream>>>(bufA, bufB, off, srow, snorm, dinv, b2, 256);
    // L3 (transform-first): t3 = h2@W3 -> bufA [NN,128]; h3 = relu(A.t3+b3) -> bufB
    {
        dim3 g(128 / 64, (NN + 63) / 64);
        gemm_kernel<0><<<g, 256, 0, stream>>>(bufB, W3, nullptr, bufA, NN, 256, 128);
    }
    aggregate_kernel<1><<<AGG_B, 256, 0, stream>>>(bufA, bufB, off, srow, snorm, dinv, b3, 128);
    // L4 (aggregate-first): agg4 = A.h3 (dim 128) -> bufA; h4 = relu(agg4@W4+b4) -> bufB [NN,200]
    aggregate_kernel<0><<<AGG_B, 256, 0, stream>>>(bufB, bufA, off, srow, snorm, dinv, nullptr, 128);
    {
        dim3 g((200 + 63) / 64, (NN + 63) / 64);
        gemm_kernel<1><<<g, 256, 0, stream>>>(bufA, W4, b4, bufB, NN, 128, 200);
    }
    mean_kernel<<<1024, 256, 0, stream>>>(bufB, out);
}

// Round 2
// 493.655 us; speedup vs baseline: 2.7905x; 2.7905x over previous
//
#include <hip/hip_runtime.h>
#include <hip/hip_bf16.h>

// GCN 4-layer, N=50000, E=800000, dims 100->512->256->128->200.
// bf16 MFMA GEMMs (weights split hi+lo for fp32-grade systematic accuracy),
// bf16 gathers for aggregation, CSR built in ws each call.

#define NN 50000
#define NE 800000

typedef __attribute__((ext_vector_type(8))) short bf16x8;
typedef __attribute__((ext_vector_type(4))) float floatx4;

__device__ __forceinline__ float b2f(unsigned short u) {
    union { unsigned u; float f; } v;
    v.u = ((unsigned)u) << 16;
    return v.f;
}
__device__ __forceinline__ unsigned short f2b(float f) {
    unsigned x = __float_as_uint(f);
    unsigned r = (x + 0x7fffu + ((x >> 16) & 1u)) >> 16;
    return (unsigned short)r;
}

// ---------------- edge-index dtype detect + CSR build ----------------
__global__ void detect_kernel(const unsigned* ei, int* flag) {
    __shared__ int nonzero;
    if (threadIdx.x == 0) nonzero = 0;
    __syncthreads();
    unsigned w = ei[2 * threadIdx.x + 1];
    if (w) atomicOr(&nonzero, 1);
    __syncthreads();
    if (threadIdx.x == 0) *flag = nonzero ? 0 : 1;  // 1 => int64
}

__global__ __launch_bounds__(256) void convert_kernel(
    const void* ei, const int* __restrict__ flag,
    int* __restrict__ row32, int* __restrict__ col32, unsigned* __restrict__ cnt) {
    int e = blockIdx.x * blockDim.x + threadIdx.x;
    if (e >= NE) return;
    int r, c;
    if (*flag) {
        const long long* p = (const long long*)ei;
        r = (int)p[e];
        c = (int)p[NE + e];
    } else {
        const int* p = (const int*)ei;
        r = p[e];
        c = p[NE + e];
    }
    row32[e] = r;
    col32[e] = c;
    atomicAdd(&cnt[c], 1u);
}

__global__ __launch_bounds__(256) void dinv_kernel(const unsigned* __restrict__ cnt,
                                                   float* __restrict__ dinv) {
    int i = blockIdx.x * blockDim.x + threadIdx.x;
    if (i >= NN) return;
    dinv[i] = rsqrtf((float)(cnt[i] + 1u));
}

// hierarchical scan: 49 blocks x 1024 elems
__global__ __launch_bounds__(256) void scan1_kernel(const unsigned* __restrict__ cnt,
                                                    int* __restrict__ off,
                                                    int* __restrict__ bsum) {
    __shared__ int ws[4];
    int b = blockIdx.x, t = threadIdx.x;
    int base = b * 1024 + t * 4;
    int v[4];
    int s = 0;
#pragma unroll
    for (int i = 0; i < 4; i++) {
        int val = (base + i < NN) ? (int)cnt[base + i] : 0;
        v[i] = s;
        s += val;
    }
    int lane = t & 63, wv = t >> 6;
    int x = s;
    for (int d = 1; d < 64; d <<= 1) {
        int y = __shfl_up(x, d, 64);
        if (lane >= d) x += y;
    }
    if (lane == 63) ws[wv] = x;
    __syncthreads();
    int wpre = 0;
#pragma unroll
    for (int i = 0; i < 4; i++)
        if (i < wv) wpre += ws[i];
    int texcl = x - s + wpre;
#pragma unroll
    for (int i = 0; i < 4; i++)
        if (base + i < NN) off[base + i] = texcl + v[i];
    if (t == 255) bsum[b] = texcl + s;
}

__global__ void scan2_kernel(int* bsum, int nb) {
    int t = threadIdx.x;
    int v = (t < nb) ? bsum[t] : 0;
    int x = v;
    for (int d = 1; d < 64; d <<= 1) {
        int y = __shfl_up(x, d, 64);
        if (t >= d) x += y;
    }
    if (t < nb) bsum[t] = x - v;
}

__global__ __launch_bounds__(256) void scan3_kernel(int* __restrict__ off,
                                                    const int* __restrict__ bsum) {
    int b = blockIdx.x;
    int add = bsum[b];
    int base = b * 1024 + threadIdx.x * 4;
#pragma unroll
    for (int i = 0; i < 4; i++)
        if (base + i < NN) off[base + i] += add;
    if (b == 0 && threadIdx.x == 0) off[NN] = NE;
}

__global__ __launch_bounds__(256) void fill_kernel(
    const int* __restrict__ row32, const int* __restrict__ col32,
    const int* __restrict__ off, unsigned* __restrict__ fillc,
    const float* __restrict__ dinv, int* __restrict__ srow, float* __restrict__ snorm) {
    int e = blockIdx.x * blockDim.x + threadIdx.x;
    if (e >= NE) return;
    int r = row32[e], c = col32[e];
    int pos = off[c] + (int)atomicAdd(&fillc[c], 1u);
    srow[pos] = r;
    snorm[pos] = dinv[r] * dinv[c];
}

// x fp32 [NN,100] -> bf16 [NN,128] zero-padded
__global__ __launch_bounds__(256) void xcast_kernel(const float* __restrict__ x,
                                                    unsigned short* __restrict__ xb) {
    int tid = blockIdx.x * 256 + threadIdx.x;
    int node = tid >> 4, sub = tid & 15;
    if (node >= NN) return;
    int base = sub * 8;
    unsigned short o[8];
#pragma unroll
    for (int i = 0; i < 8; i++) {
        int c = base + i;
        float v = (c < 100) ? x[(size_t)node * 100 + c] : 0.f;
        o[i] = f2b(v);
    }
    uint4 pk;
    pk.x = (unsigned)o[0] | ((unsigned)o[1] << 16);
    pk.y = (unsigned)o[2] | ((unsigned)o[3] << 16);
    pk.z = (unsigned)o[4] | ((unsigned)o[5] << 16);
    pk.w = (unsigned)o[6] | ((unsigned)o[7] << 16);
    *(uint4*)(xb + (size_t)node * 128 + base) = pk;
}

// W [K,N] fp32 -> Wt_hi/Wt_lo [Npad,Kpad] bf16 (transposed, zero-padded)
__global__ __launch_bounds__(256) void wsplit_kernel(
    const float* __restrict__ W, unsigned short* __restrict__ Wh,
    unsigned short* __restrict__ Wl, int K, int N, int Kpad, int Npad) {
    int tid = blockIdx.x * 256 + threadIdx.x;
    if (tid >= Kpad * Npad) return;
    int n = tid / Kpad, k = tid - n * Kpad;
    float v = (k < K && n < N) ? W[(size_t)k * N + n] : 0.f;
    unsigned short hi = f2b(v);
    unsigned short lo = f2b(v - b2f(hi));
    Wh[tid] = hi;
    Wl[tid] = lo;
}

__device__ __forceinline__ void load8(const unsigned short* p, float* f) {
    uint4 v = *(const uint4*)p;
    unsigned a0 = v.x, a1 = v.y, a2 = v.z, a3 = v.w;
    f[0] = b2f((unsigned short)(a0 & 0xffffu));
    f[1] = b2f((unsigned short)(a0 >> 16));
    f[2] = b2f((unsigned short)(a1 & 0xffffu));
    f[3] = b2f((unsigned short)(a1 >> 16));
    f[4] = b2f((unsigned short)(a2 & 0xffffu));
    f[5] = b2f((unsigned short)(a2 >> 16));
    f[6] = b2f((unsigned short)(a3 & 0xffffu));
    f[7] = b2f((unsigned short)(a3 >> 16));
}

// aggregation: D/8 lanes per node, bf16 in, bf16 out. BR=1: bias+relu epilogue.
template <int D, int BR>
__global__ __launch_bounds__(256) void agg_kernel(
    const unsigned short* __restrict__ H, const int* __restrict__ off,
    const int* __restrict__ srow, const float* __restrict__ snorm,
    const float* __restrict__ dinv, const float* __restrict__ bias,
    unsigned short* __restrict__ O) {
    constexpr int LPN = D / 8;
    int tid = blockIdx.x * 256 + threadIdx.x;
    int node = tid / LPN;
    int sub = tid % LPN;
    if (node >= NN) return;
    int s = off[node], e = off[node + 1];
    float dc = dinv[node];
    float selfw = dc * dc;
    const int base = sub * 8;
    float acc[8], t[8];
    load8(H + (size_t)node * D + base, t);
#pragma unroll
    for (int i = 0; i < 8; i++) acc[i] = selfw * t[i];
    for (int j = s; j < e; ++j) {
        int r = srow[j];
        float w = snorm[j];
        load8(H + (size_t)r * D + base, t);
#pragma unroll
        for (int i = 0; i < 8; i++) acc[i] = fmaf(w, t[i], acc[i]);
    }
    if (BR) {
#pragma unroll
        for (int i = 0; i < 8; i++) acc[i] = fmaxf(acc[i] + bias[base + i], 0.f);
    }
    unsigned short o[8];
#pragma unroll
    for (int i = 0; i < 8; i++) o[i] = f2b(acc[i]);
    uint4 pk;
    pk.x = (unsigned)o[0] | ((unsigned)o[1] << 16);
    pk.y = (unsigned)o[2] | ((unsigned)o[3] << 16);
    pk.z = (unsigned)o[4] | ((unsigned)o[5] << 16);
    pk.w = (unsigned)o[6] | ((unsigned)o[7] << 16);
    *(uint4*)(O + (size_t)node * D + base) = pk;
}

// MFMA GEMM: C[M,N] = A[M,K] @ (Bh+Bl)^T where Bh/Bl are [Npad,K] bf16.
// 128x128 tile, 256 threads (4 waves, 2x2 of 64x64), 16x16x32 bf16 MFMA.
// EPI: 0 = store bf16, 1 = bias+relu store bf16, 2 = fused column-mean atomic.
template <int EPI>
__global__ __launch_bounds__(256) void gemm_kernel(
    const unsigned short* __restrict__ A, const unsigned short* __restrict__ Bh,
    const unsigned short* __restrict__ Bl, const float* __restrict__ bias,
    unsigned short* __restrict__ Cb, float* __restrict__ outmean,
    int M, int K, int N) {
    __shared__ unsigned short Asl[128 * 32];
    __shared__ unsigned short Bhl[128 * 32];
    __shared__ unsigned short Bll[128 * 32];
    __shared__ float red[128];
    const int m0 = blockIdx.y * 128;
    const int n0 = blockIdx.x * 128;
    const int t = threadIdx.x;
    const int lane = t & 63, w = t >> 6;
    const int wm = (w >> 1) * 64, wn = (w & 1) * 64;
    const int r16 = lane & 15, quad = lane >> 4;

    floatx4 acc[4][4];
    const floatx4 fz = {0.f, 0.f, 0.f, 0.f};
#pragma unroll
    for (int i = 0; i < 4; i++)
#pragma unroll
        for (int j = 0; j < 4; j++) acc[i][j] = fz;

    for (int kc = 0; kc < K; kc += 32) {
        __syncthreads();
#pragma unroll
        for (int i = 0; i < 2; i++) {
            int seg = t + 256 * i;
            int row = seg >> 2, k8 = (seg & 3) * 8;
            int gm = m0 + row;
            if (gm > M - 1) gm = M - 1;
            *(uint4*)(Asl + row * 32 + k8) = *(const uint4*)(A + (size_t)gm * K + kc + k8);
            int gn = n0 + row;  // B padded to Npad multiple of 128
            *(uint4*)(Bhl + row * 32 + k8) = *(const uint4*)(Bh + (size_t)gn * K + kc + k8);
            *(uint4*)(Bll + row * 32 + k8) = *(const uint4*)(Bl + (size_t)gn * K + kc + k8);
        }
        __syncthreads();
        bf16x8 af[4], bhf[4], blf[4];
#pragma unroll
        for (int i = 0; i < 4; i++)
            af[i] = *(const bf16x8*)(Asl + (wm + i * 16 + r16) * 32 + quad * 8);
#pragma unroll
        for (int j = 0; j < 4; j++) {
            bhf[j] = *(const bf16x8*)(Bhl + (wn + j * 16 + r16) * 32 + quad * 8);
            blf[j] = *(const bf16x8*)(Bll + (wn + j * 16 + r16) * 32 + quad * 8);
        }
#pragma unroll
        for (int i = 0; i < 4; i++)
#pragma unroll
            for (int j = 0; j < 4; j++) {
                acc[i][j] = __builtin_amdgcn_mfma_f32_16x16x32_bf16(af[i], bhf[j], acc[i][j], 0, 0, 0);
                acc[i][j] = __builtin_amdgcn_mfma_f32_16x16x32_bf16(af[i], blf[j], acc[i][j], 0, 0, 0);
            }
    }

    if (EPI == 2) {
        if (t < 128) red[t] = 0.f;
        __syncthreads();
#pragma unroll
        for (int j = 0; j < 4; j++) {
            int col = n0 + wn + j * 16 + r16;
            float s = 0.f;
            if (col < N) {
                float bv = bias[col];
#pragma unroll
                for (int i = 0; i < 4; i++)
#pragma unroll
                    for (int r = 0; r < 4; r++) {
                        int m = m0 + wm + i * 16 + quad * 4 + r;
                        if (m < M) s += fmaxf(acc[i][j][r] + bv, 0.f);
                    }
            }
            atomicAdd(&red[wn + j * 16 + r16], s);
        }
        __syncthreads();
        if (t < 128) {
            int col = n0 + t;
            if (col < N) atomicAdd(outmean + col, red[t] * (1.0f / (float)NN));
        }
    } else {
#pragma unroll
        for (int i = 0; i < 4; i++)
#pragma unroll
            for (int r = 0; r < 4; r++) {
                int m = m0 + wm + i * 16 + quad * 4 + r;
                if (m >= M) continue;
#pragma unroll
                for (int j = 0; j < 4; j++) {
                    int col = n0 + wn + j * 16 + r16;
                    float v = acc[i][j][r];
                    if (EPI == 1) v = fmaxf(v + bias[col], 0.f);
                    Cb[(size_t)m * N + col] = f2b(v);
                }
            }
    }
}

extern "C" void kernel_launch(void* const* d_in, const int* in_sizes, int n_in,
                              void* d_out, int out_size, void* d_ws, size_t ws_size,
                              hipStream_t stream) {
    const float* x  = (const float*)d_in[0];
    const void*  ei = d_in[1];
    const float* W1 = (const float*)d_in[2];
    const float* b1 = (const float*)d_in[3];
    const float* W2 = (const float*)d_in[4];
    const float* b2 = (const float*)d_in[5];
    const float* W3 = (const float*)d_in[6];
    const float* b3 = (const float*)d_in[7];
    const float* W4 = (const float*)d_in[8];
    const float* b4 = (const float*)d_in[9];
    float* out = (float*)d_out;

    char* ws = (char*)d_ws;
    size_t o = 0;
    auto alloc = [&](size_t bytes) -> void* {
        void* p = ws + o;
        o += (bytes + 255) & ~(size_t)255;
        return p;
    };
    int*      flag  = (int*)alloc(4);
    int*      row32 = (int*)alloc((size_t)NE * 4);
    int*      col32 = (int*)alloc((size_t)NE * 4);
    unsigned* cnt   = (unsigned*)alloc((size_t)NN * 4);
    int*      off   = (int*)alloc((size_t)(NN + 1) * 4);
    unsigned* fillc = (unsigned*)alloc((size_t)NN * 4);
    float*    dinv  = (float*)alloc((size_t)NN * 4);
    int*      srow  = (int*)alloc((size_t)NE * 4);
    float*    snorm = (float*)alloc((size_t)NE * 4);
    int*      bsum  = (int*)alloc(256);
    unsigned short* w1h = (unsigned short*)alloc((size_t)512 * 128 * 2);
    unsigned short* w1l = (unsigned short*)alloc((size_t)512 * 128 * 2);
    unsigned short* w2h = (unsigned short*)alloc((size_t)256 * 512 * 2);
    unsigned short* w2l = (unsigned short*)alloc((size_t)256 * 512 * 2);
    unsigned short* w3h = (unsigned short*)alloc((size_t)128 * 256 * 2);
    unsigned short* w3l = (unsigned short*)alloc((size_t)128 * 256 * 2);
    unsigned short* w4h = (unsigned short*)alloc((size_t)256 * 128 * 2);
    unsigned short* w4l = (unsigned short*)alloc((size_t)256 * 128 * 2);
    // arenas with lifetime overlays
    unsigned short* arena1 = (unsigned short*)alloc((size_t)NN * 512 * 2);  // 51.2 MB
    unsigned short* arena2 = (unsigned short*)alloc((size_t)NN * 256 * 2);  // 25.6 MB
    unsigned short* arena3 = (unsigned short*)alloc((size_t)NN * 256 * 2);  // 25.6 MB
    unsigned short* xb  = arena1;  // [NN,128], dead after agg1
    unsigned short* A1b = arena2;  // [NN,128], dead after gemm1
    unsigned short* H1b = arena1;  // [NN,512], dead after gemm2
    unsigned short* t2b = arena2;  // [NN,256], dead after agg2
    unsigned short* H2b = arena3;  // [NN,256], dead after gemm3
    unsigned short* t3b = arena1;  // [NN,128], dead after agg3
    unsigned short* h3b = arena2;  // [NN,128], dead after agg4
    unsigned short* A4b = arena1;  // [NN,128], dead after gemm4

    hipMemsetAsync(cnt, 0, (size_t)NN * 4, stream);
    hipMemsetAsync(fillc, 0, (size_t)NN * 4, stream);
    hipMemsetAsync(out, 0, 200 * 4, stream);

    const int EB = (NE + 255) / 256;  // 3125
    const int NB1 = (NN + 1023) / 1024;  // 49

    detect_kernel<<<1, 256, 0, stream>>>((const unsigned*)ei, flag);
    convert_kernel<<<EB, 256, 0, stream>>>(ei, flag, row32, col32, cnt);
    dinv_kernel<<<(NN + 255) / 256, 256, 0, stream>>>(cnt, dinv);
    scan1_kernel<<<NB1, 256, 0, stream>>>(cnt, off, bsum);
    scan2_kernel<<<1, 64, 0, stream>>>(bsum, NB1);
    scan3_kernel<<<NB1, 256, 0, stream>>>(off, bsum);
    fill_kernel<<<EB, 256, 0, stream>>>(row32, col32, off, fillc, dinv, srow, snorm);

    xcast_kernel<<<(NN * 16 + 255) / 256, 256, 0, stream>>>(x, xb);
    wsplit_kernel<<<(512 * 128 + 255) / 256, 256, 0, stream>>>(W1, w1h, w1l, 100, 512, 128, 512);
    wsplit_kernel<<<(256 * 512 + 255) / 256, 256, 0, stream>>>(W2, w2h, w2l, 512, 256, 512, 256);
    wsplit_kernel<<<(128 * 256 + 255) / 256, 256, 0, stream>>>(W3, w3h, w3l, 256, 128, 256, 128);
    wsplit_kernel<<<(256 * 128 + 255) / 256, 256, 0, stream>>>(W4, w4h, w4l, 128, 200, 128, 256);

    const int MB = (NN + 127) / 128;  // 391

    // L1: agg(x) -> A1, gemm -> relu -> H1 [NN,512]
    agg_kernel<128, 0><<<(NN * 16 + 255) / 256, 256, 0, stream>>>(xb, off, srow, snorm, dinv, nullptr, A1b);
    gemm_kernel<1><<<dim3(4, MB), 256, 0, stream>>>(A1b, w1h, w1l, b1, H1b, nullptr, NN, 128, 512);
    // L2: gemm H1 -> t2 [NN,256]; agg+bias+relu -> H2
    gemm_kernel<0><<<dim3(2, MB), 256, 0, stream>>>(H1b, w2h, w2l, nullptr, t2b, nullptr, NN, 512, 256);
    agg_kernel<256, 1><<<(NN * 32 + 255) / 256, 256, 0, stream>>>(t2b, off, srow, snorm, dinv, b2, H2b);
    // L3: gemm H2 -> t3 [NN,128]; agg+bias+relu -> h3
    gemm_kernel<0><<<dim3(1, MB), 256, 0, stream>>>(H2b, w3h, w3l, nullptr, t3b, nullptr, NN, 256, 128);
    agg_kernel<128, 1><<<(NN * 16 + 255) / 256, 256, 0, stream>>>(t3b, off, srow, snorm, dinv, b3, h3b);
    // L4: agg(h3) -> A4; gemm + bias + relu + fused column mean -> out
    agg_kernel<128, 0><<<(NN * 16 + 255) / 256, 256, 0, stream>>>(h3b, off, srow, snorm, dinv, nullptr, A4b);
    gemm_kernel<2><<<dim3(2, MB), 256, 0, stream>>>(A4b, w4h, w4l, b4, nullptr, out, NN, 128, 200);
}

// Round 3
// 443.781 us; speedup vs baseline: 3.1041x; 1.1124x over previous
//
#include <hip/hip_runtime.h>
#include <hip/hip_bf16.h>

// GCN 4-layer, N=50000, E=800000, dims 100->512->256->128->200.
// fp16 MFMA GEMMs (single pass, fp16 >= bf16 hi/lo accuracy here),
// fp16 gathers with x2-unrolled edge loop, CSR built in ws each call.

#define NN 50000
#define NE 800000

typedef __attribute__((ext_vector_type(8))) _Float16 f16x8;
typedef __attribute__((ext_vector_type(4))) float floatx4;

union U16x8 {
    uint4 u4;
    f16x8 h;
    _Float16 e[8];
};

// ---------------- edge-index dtype detect ----------------
// int64 little-endian with values in [0, 50000) => every odd 32-bit word == 0.
__global__ void detect_kernel(const unsigned* ei, int* flag) {
    __shared__ int nonzero;
    if (threadIdx.x == 0) nonzero = 0;
    __syncthreads();
    unsigned w = ei[2 * threadIdx.x + 1];
    if (w) atomicOr(&nonzero, 1);
    __syncthreads();
    if (threadIdx.x == 0) *flag = nonzero ? 0 : 1;  // 1 => int64
}

__device__ __forceinline__ int load_idx(const void* ei, int isflag64, size_t pos) {
    if (isflag64) return (int)((const long long*)ei)[pos];
    return ((const int*)ei)[pos];
}

__global__ __launch_bounds__(256) void count_kernel(const void* ei,
                                                    const int* __restrict__ flag,
                                                    unsigned* __restrict__ cnt) {
    int e = blockIdx.x * blockDim.x + threadIdx.x;
    if (e >= NE) return;
    int c = load_idx(ei, *flag, (size_t)NE + e);
    atomicAdd(&cnt[c], 1u);
}

__global__ __launch_bounds__(256) void dinv_kernel(const unsigned* __restrict__ cnt,
                                                   float* __restrict__ dinv) {
    int i = blockIdx.x * blockDim.x + threadIdx.x;
    if (i >= NN) return;
    dinv[i] = rsqrtf((float)(cnt[i] + 1u));
}

// hierarchical scan: 49 blocks x 1024 elems
__global__ __launch_bounds__(256) void scan1_kernel(const unsigned* __restrict__ cnt,
                                                    int* __restrict__ off,
                                                    int* __restrict__ bsum) {
    __shared__ int ws[4];
    int b = blockIdx.x, t = threadIdx.x;
    int base = b * 1024 + t * 4;
    int v[4];
    int s = 0;
#pragma unroll
    for (int i = 0; i < 4; i++) {
        int val = (base + i < NN) ? (int)cnt[base + i] : 0;
        v[i] = s;
        s += val;
    }
    int lane = t & 63, wv = t >> 6;
    int x = s;
    for (int d = 1; d < 64; d <<= 1) {
        int y = __shfl_up(x, d, 64);
        if (lane >= d) x += y;
    }
    if (lane == 63) ws[wv] = x;
    __syncthreads();
    int wpre = 0;
#pragma unroll
    for (int i = 0; i < 4; i++)
        if (i < wv) wpre += ws[i];
    int texcl = x - s + wpre;
#pragma unroll
    for (int i = 0; i < 4; i++)
        if (base + i < NN) off[base + i] = texcl + v[i];
    if (t == 255) bsum[b] = texcl + s;
}

__global__ void scan2_kernel(int* bsum, int nb) {
    int t = threadIdx.x;
    int v = (t < nb) ? bsum[t] : 0;
    int x = v;
    for (int d = 1; d < 64; d <<= 1) {
        int y = __shfl_up(x, d, 64);
        if (t >= d) x += y;
    }
    if (t < nb) bsum[t] = x - v;
}

__global__ __launch_bounds__(256) void scan3_kernel(int* __restrict__ off,
                                                    const int* __restrict__ bsum) {
    int b = blockIdx.x;
    int add = bsum[b];
    int base = b * 1024 + threadIdx.x * 4;
#pragma unroll
    for (int i = 0; i < 4; i++)
        if (base + i < NN) off[base + i] += add;
    if (b == 0 && threadIdx.x == 0) off[NN] = NE;
}

// fill CSR: ep[pos] = {src_row, bitcast(norm)}
__global__ __launch_bounds__(256) void fill_kernel(
    const void* ei, const int* __restrict__ flag, const int* __restrict__ off,
    unsigned* __restrict__ fillc, const float* __restrict__ dinv,
    int2* __restrict__ ep) {
    int e = blockIdx.x * blockDim.x + threadIdx.x;
    if (e >= NE) return;
    int f64 = *flag;
    int r = load_idx(ei, f64, e);
    int c = load_idx(ei, f64, (size_t)NE + e);
    int pos = off[c] + (int)atomicAdd(&fillc[c], 1u);
    int2 v;
    v.x = r;
    v.y = __float_as_int(dinv[r] * dinv[c]);
    ep[pos] = v;
}

// x fp32 [NN,100] -> f16 [NN,128] zero-padded
__global__ __launch_bounds__(256) void xcast_kernel(const float* __restrict__ x,
                                                    _Float16* __restrict__ xb) {
    int tid = blockIdx.x * 256 + threadIdx.x;
    int node = tid >> 4, sub = tid & 15;
    if (node >= NN) return;
    int base = sub * 8;
    U16x8 o;
#pragma unroll
    for (int i = 0; i < 8; i++) {
        int c = base + i;
        float v = (c < 100) ? x[(size_t)node * 100 + c] : 0.f;
        o.e[i] = (_Float16)v;
    }
    *(uint4*)(xb + (size_t)node * 128 + base) = o.u4;
}

// W [K,N] fp32 -> Wt [Npad,Kpad] f16 (transposed, zero-padded)
__global__ __launch_bounds__(256) void wcast_kernel(const float* __restrict__ W,
                                                    _Float16* __restrict__ Wt,
                                                    int K, int N, int Kpad, int Npad) {
    int tid = blockIdx.x * 256 + threadIdx.x;
    if (tid >= Kpad * Npad) return;
    int n = tid / Kpad, k = tid - n * Kpad;
    float v = (k < K && n < N) ? W[(size_t)k * N + n] : 0.f;
    Wt[tid] = (_Float16)v;
}

__device__ __forceinline__ void load8h(const _Float16* p, float* f) {
    U16x8 v;
    v.u4 = *(const uint4*)p;
#pragma unroll
    for (int i = 0; i < 8; i++) f[i] = (float)v.e[i];
}

// aggregation: D/8 lanes per node, f16 in/out, fp32 accumulate.
// Edge loop unrolled x2 for memory-level parallelism.
template <int D, int BR>
__global__ __launch_bounds__(256) void agg_kernel(
    const _Float16* __restrict__ H, const int* __restrict__ off,
    const int2* __restrict__ ep, const float* __restrict__ dinv,
    const float* __restrict__ bias, _Float16* __restrict__ O) {
    constexpr int LPN = D / 8;
    int tid = blockIdx.x * 256 + threadIdx.x;
    int node = tid / LPN;
    int sub = tid % LPN;
    if (node >= NN) return;
    int s = off[node], e = off[node + 1];
    float dc = dinv[node];
    float selfw = dc * dc;
    const int base = sub * 8;
    float acc[8], t0[8], t1[8];
    load8h(H + (size_t)node * D + base, t0);
#pragma unroll
    for (int i = 0; i < 8; i++) acc[i] = selfw * t0[i];
    int j = s;
    for (; j + 2 <= e; j += 2) {
        int2 e0 = ep[j];
        int2 e1 = ep[j + 1];
        load8h(H + (size_t)e0.x * D + base, t0);
        load8h(H + (size_t)e1.x * D + base, t1);
        float w0 = __int_as_float(e0.y);
        float w1 = __int_as_float(e1.y);
#pragma unroll
        for (int i = 0; i < 8; i++) acc[i] = fmaf(w0, t0[i], acc[i]);
#pragma unroll
        for (int i = 0; i < 8; i++) acc[i] = fmaf(w1, t1[i], acc[i]);
    }
    if (j < e) {
        int2 e0 = ep[j];
        load8h(H + (size_t)e0.x * D + base, t0);
        float w0 = __int_as_float(e0.y);
#pragma unroll
        for (int i = 0; i < 8; i++) acc[i] = fmaf(w0, t0[i], acc[i]);
    }
    if (BR) {
#pragma unroll
        for (int i = 0; i < 8; i++) acc[i] = fmaxf(acc[i] + bias[base + i], 0.f);
    }
    U16x8 o;
#pragma unroll
    for (int i = 0; i < 8; i++) o.e[i] = (_Float16)acc[i];
    *(uint4*)(O + (size_t)node * D + base) = o.u4;
}

// MFMA GEMM: C[M,N] = A[M,K] @ B^T, B is [Npad,K] f16.
// 128x128 tile, 256 threads (2x2 waves of 64x64), 16x16x32 f16 MFMA.
// LDS row stride 40 elems (80 B) to break 8-way bank aliasing.
// EPI: 0 = store f16, 1 = bias+relu store f16, 2 = bias+relu+column-mean atomic.
template <int EPI>
__global__ __launch_bounds__(256) void gemm_kernel(
    const _Float16* __restrict__ A, const _Float16* __restrict__ B,
    const float* __restrict__ bias, _Float16* __restrict__ Cb,
    float* __restrict__ outmean, int M, int K, int N) {
    __shared__ _Float16 Asl[128 * 40];
    __shared__ _Float16 Bsl[128 * 40];
    __shared__ float red[128];
    const int m0 = blockIdx.y * 128;
    const int n0 = blockIdx.x * 128;
    const int t = threadIdx.x;
    const int lane = t & 63, w = t >> 6;
    const int wm = (w >> 1) * 64, wn = (w & 1) * 64;
    const int r16 = lane & 15, quad = lane >> 4;

    floatx4 acc[4][4];
    const floatx4 fz = {0.f, 0.f, 0.f, 0.f};
#pragma unroll
    for (int i = 0; i < 4; i++)
#pragma unroll
        for (int j = 0; j < 4; j++) acc[i][j] = fz;

    for (int kc = 0; kc < K; kc += 32) {
        __syncthreads();
#pragma unroll
        for (int i = 0; i < 2; i++) {
            int seg = t + 256 * i;
            int row = seg >> 2, k8 = (seg & 3) * 8;
            int gm = m0 + row;
            if (gm > M - 1) gm = M - 1;
            *(uint4*)(Asl + row * 40 + k8) = *(const uint4*)(A + (size_t)gm * K + kc + k8);
            int gn = n0 + row;  // B padded to Npad multiple of 128
            *(uint4*)(Bsl + row * 40 + k8) = *(const uint4*)(B + (size_t)gn * K + kc + k8);
        }
        __syncthreads();
        f16x8 af[4], bf[4];
#pragma unroll
        for (int i = 0; i < 4; i++)
            af[i] = *(const f16x8*)(Asl + (wm + i * 16 + r16) * 40 + quad * 8);
#pragma unroll
        for (int j = 0; j < 4; j++)
            bf[j] = *(const f16x8*)(Bsl + (wn + j * 16 + r16) * 40 + quad * 8);
#pragma unroll
        for (int i = 0; i < 4; i++)
#pragma unroll
            for (int j = 0; j < 4; j++)
                acc[i][j] = __builtin_amdgcn_mfma_f32_16x16x32_f16(af[i], bf[j], acc[i][j], 0, 0, 0);
    }

    if (EPI == 2) {
        if (t < 128) red[t] = 0.f;
        __syncthreads();
#pragma unroll
        for (int j = 0; j < 4; j++) {
            int col = n0 + wn + j * 16 + r16;
            float s = 0.f;
            if (col < N) {
                float bv = bias[col];
#pragma unroll
                for (int i = 0; i < 4; i++)
#pragma unroll
                    for (int r = 0; r < 4; r++) {
                        int m = m0 + wm + i * 16 + quad * 4 + r;
                        if (m < M) s += fmaxf(acc[i][j][r] + bv, 0.f);
                    }
            }
            atomicAdd(&red[wn + j * 16 + r16], s);
        }
        __syncthreads();
        if (t < 128) {
            int col = n0 + t;
            if (col < N) atomicAdd(outmean + col, red[t] * (1.0f / (float)NN));
        }
    } else {
#pragma unroll
        for (int i = 0; i < 4; i++)
#pragma unroll
            for (int r = 0; r < 4; r++) {
                int m = m0 + wm + i * 16 + quad * 4 + r;
                if (m >= M) continue;
#pragma unroll
                for (int j = 0; j < 4; j++) {
                    int col = n0 + wn + j * 16 + r16;
                    float v = acc[i][j][r];
                    if (EPI == 1) v = fmaxf(v + bias[col], 0.f);
                    Cb[(size_t)m * N + col] = (_Float16)v;
                }
            }
    }
}

extern "C" void kernel_launch(void* const* d_in, const int* in_sizes, int n_in,
                              void* d_out, int out_size, void* d_ws, size_t ws_size,
                              hipStream_t stream) {
    const float* x  = (const float*)d_in[0];
    const void*  ei = d_in[1];
    const float* W1 = (const float*)d_in[2];
    const float* b1 = (const float*)d_in[3];
    const float* W2 = (const float*)d_in[4];
    const float* b2 = (const float*)d_in[5];
    const float* W3 = (const float*)d_in[6];
    const float* b3 = (const float*)d_in[7];
    const float* W4 = (const float*)d_in[8];
    const float* b4 = (const float*)d_in[9];
    float* out = (float*)d_out;

    char* ws = (char*)d_ws;
    size_t o = 0;
    auto alloc = [&](size_t bytes) -> void* {
        void* p = ws + o;
        o += (bytes + 255) & ~(size_t)255;
        return p;
    };
    int*      flag  = (int*)alloc(4);
    unsigned* cnt   = (unsigned*)alloc((size_t)NN * 4);
    int*      off   = (int*)alloc((size_t)(NN + 1) * 4);
    unsigned* fillc = (unsigned*)alloc((size_t)NN * 4);
    float*    dinv  = (float*)alloc((size_t)NN * 4);
    int2*     ep    = (int2*)alloc((size_t)NE * 8);
    int*      bsum  = (int*)alloc(256);
    _Float16* w1t = (_Float16*)alloc((size_t)512 * 128 * 2);
    _Float16* w2t = (_Float16*)alloc((size_t)256 * 512 * 2);
    _Float16* w3t = (_Float16*)alloc((size_t)128 * 256 * 2);
    _Float16* w4t = (_Float16*)alloc((size_t)256 * 128 * 2);
    // arenas with lifetime overlays
    _Float16* arena1 = (_Float16*)alloc((size_t)NN * 512 * 2);  // 51.2 MB
    _Float16* arena2 = (_Float16*)alloc((size_t)NN * 256 * 2);  // 25.6 MB
    _Float16* arena3 = (_Float16*)alloc((size_t)NN * 256 * 2);  // 25.6 MB
    _Float16* xb  = arena1;  // [NN,128], dead after agg1
    _Float16* A1b = arena2;  // [NN,128], dead after gemm1
    _Float16* H1b = arena1;  // [NN,512], dead after gemm2
    _Float16* t2b = arena2;  // [NN,256], dead after agg2
    _Float16* H2b = arena3;  // [NN,256], dead after gemm3
    _Float16* t3b = arena1;  // [NN,128], dead after agg3
    _Float16* h3b = arena2;  // [NN,128], dead after agg4
    _Float16* A4b = arena1;  // [NN,128], dead after gemm4

    hipMemsetAsync(cnt, 0, (size_t)NN * 4, stream);
    hipMemsetAsync(fillc, 0, (size_t)NN * 4, stream);
    hipMemsetAsync(out, 0, 200 * 4, stream);

    const int EB = (NE + 255) / 256;     // 3125
    const int NB1 = (NN + 1023) / 1024;  // 49

    detect_kernel<<<1, 256, 0, stream>>>((const unsigned*)ei, flag);
    count_kernel<<<EB, 256, 0, stream>>>(ei, flag, cnt);
    dinv_kernel<<<(NN + 255) / 256, 256, 0, stream>>>(cnt, dinv);
    scan1_kernel<<<NB1, 256, 0, stream>>>(cnt, off, bsum);
    scan2_kernel<<<1, 64, 0, stream>>>(bsum, NB1);
    scan3_kernel<<<NB1, 256, 0, stream>>>(off, bsum);
    fill_kernel<<<EB, 256, 0, stream>>>(ei, flag, off, fillc, dinv, ep);

    xcast_kernel<<<(NN * 16 + 255) / 256, 256, 0, stream>>>(x, xb);
    wcast_kernel<<<(512 * 128 + 255) / 256, 256, 0, stream>>>(W1, w1t, 100, 512, 128, 512);
    wcast_kernel<<<(256 * 512 + 255) / 256, 256, 0, stream>>>(W2, w2t, 512, 256, 512, 256);
    wcast_kernel<<<(128 * 256 + 255) / 256, 256, 0, stream>>>(W3, w3t, 256, 128, 256, 128);
    wcast_kernel<<<(256 * 128 + 255) / 256, 256, 0, stream>>>(W4, w4t, 128, 200, 128, 256);

    const int MB = (NN + 127) / 128;  // 391

    // L1: agg(x) -> A1; gemm + bias + relu -> H1 [NN,512]
    agg_kernel<128, 0><<<(NN * 16 + 255) / 256, 256, 0, stream>>>(xb, off, ep, dinv, nullptr, A1b);
    gemm_kernel<1><<<dim3(4, MB), 256, 0, stream>>>(A1b, w1t, b1, H1b, nullptr, NN, 128, 512);
    // L2: gemm H1 -> t2 [NN,256]; agg + bias + relu -> H2
    gemm_kernel<0><<<dim3(2, MB), 256, 0, stream>>>(H1b, w2t, nullptr, t2b, nullptr, NN, 512, 256);
    agg_kernel<256, 1><<<(NN * 32 + 255) / 256, 256, 0, stream>>>(t2b, off, ep, dinv, b2, H2b);
    // L3: gemm H2 -> t3 [NN,128]; agg + bias + relu -> h3
    gemm_kernel<0><<<dim3(1, MB), 256, 0, stream>>>(H2b, w3t, nullptr, t3b, nullptr, NN, 256, 128);
    agg_kernel<128, 1><<<(NN * 16 + 255) / 256, 256, 0, stream>>>(t3b, off, ep, dinv, b3, h3b);
    // L4: agg(h3) -> A4; gemm + bias + relu + fused column mean -> out
    agg_kernel<128, 0><<<(NN * 16 + 255) / 256, 256, 0, stream>>>(h3b, off, ep, dinv, nullptr, A4b);
    gemm_kernel<2><<<dim3(2, MB), 256, 0, stream>>>(A4b, w4t, b4, nullptr, out, NN, 128, 200);
}